// Round 14
// baseline (308.906 us; speedup 1.0000x reference)
//
#include <hip/hip_runtime.h>

// GATv2 3-layer + mean-pool + linear head, MI355X.
// R33 = R32 (295.8us best) + padded chunk-0 srcs table. Attn's per-dst chain
// was off[d] -> srcs[lo+min(..)] -> gather; pad[NN][32] (u16, prefilled with
// d by k_prep, dual-written by k_scatter_rank for slots<32) makes the 8
// chunk-0 srcs loads depend only on d0/d1 -> they issue at wave start in
// parallel with off loads (one L2 round-trip + 8 clamps off the chain).
// deg>32 continuation keeps the CSR path. Everything else = R32/R30:
// fused-serial g0+hist (interleave measured worse), 2-dst/wave attn with
// per-dst gating, VALU-pipe reduces, 11-dispatch pipeline.

#define NN 50000
#define NE 1000000
#define HID 64
#define DIN0 128
#define NG 256
#define NEG 0.2f

#define SCHUNK 1024
#define SNB ((NN + SCHUNK - 1) / SCHUNK)   // 49 blocks
#define G0B ((NN + 63) / 64)               // 782 gemm-L0 blocks
#define HB 512                             // hist8 blocks

typedef float f32x4 __attribute__((ext_vector_type(4)));
typedef short s8v __attribute__((ext_vector_type(8)));
typedef short s4v __attribute__((ext_vector_type(4)));
typedef __bf16 bf16x8 __attribute__((ext_vector_type(8)));
typedef _Float16 h2v __attribute__((ext_vector_type(2)));
typedef unsigned u32x2 __attribute__((ext_vector_type(2)));
typedef unsigned short u16;

__device__ __forceinline__ unsigned short f2bf(float f) {
    unsigned u = __float_as_uint(f);
    u = u + 0x7fffu + ((u >> 16) & 1u);   // RNE
    return (unsigned short)(u >> 16);
}
__device__ __forceinline__ float bf2f(unsigned short v) {
    return __uint_as_float(((unsigned)v) << 16);
}
__device__ __forceinline__ short split_hi(float x) {
    return (short)f2bf(x);
}
__device__ __forceinline__ short split_lo(float x, short hi) {
    return (short)f2bf(x - bf2f((unsigned short)hi));
}
__device__ __forceinline__ h2v u2h(unsigned u) { return __builtin_bit_cast(h2v, u); }
__device__ __forceinline__ unsigned h2u(h2v h) { return __builtin_bit_cast(unsigned, h); }
// (b.lo16 << 16) | a.lo16  and  (b.hi16 << 16) | a.hi16  - one v_perm_b32 each
__device__ __forceinline__ h2v pklo(unsigned a, unsigned b) {
    return u2h(__builtin_amdgcn_perm(b, a, 0x05040100u));
}
__device__ __forceinline__ h2v pkhi(unsigned a, unsigned b) {
    return u2h(__builtin_amdgcn_perm(b, a, 0x07060302u));
}
// cross-lane primitives on the VALU pipe (DPP / permlane) + ds_swizzle
template <int CTRL>
__device__ __forceinline__ float dpp_mv(float v) {   // value from lane per CTRL
    return __int_as_float(
        __builtin_amdgcn_update_dpp(0, __float_as_int(v), CTRL, 0xF, 0xF, true));
}
template <int OFF>
__device__ __forceinline__ float swz(float v) {      // ds_swizzle xor mode
    return __int_as_float(__builtin_amdgcn_ds_swizzle(__float_as_int(v), OFF));
}
__device__ __forceinline__ float red32_add(float v) {
    unsigned u = __float_as_uint(v);
    u32x2 r = __builtin_amdgcn_permlane32_swap(u, u, false, false);
    return __uint_as_float(r[0]) + __uint_as_float(r[1]);
}
__device__ __forceinline__ float red32_max(float v) {
    unsigned u = __float_as_uint(v);
    u32x2 r = __builtin_amdgcn_permlane32_swap(u, u, false, false);
    return fmaxf(__uint_as_float(r[0]), __uint_as_float(r[1]));
}
// sum over the 8 cg lanes of an octet: xor1(DPP) xor2(DPP) xor4(swizzle)
__device__ __forceinline__ float octet_sum(float v) {
    v += dpp_mv<0xB1>(v);        // quad_perm(1,0,3,2) == xor1
    v += dpp_mv<0x4E>(v);        // quad_perm(2,3,0,1) == xor2
    v += swz<0x101F>(v);         // xor4
    return v;
}
// sum/max over the 8 e-slots: xor8(DPP row_ror:8) xor16(swizzle) xor32(permlane)
__device__ __forceinline__ float esum(float v) {
    v += dpp_mv<0x128>(v);       // row_ror:8 == xor8
    v += swz<0x401F>(v);         // xor16
    return red32_add(v);
}
__device__ __forceinline__ float emax(float v) {
    v = fmaxf(v, dpp_mv<0x128>(v));
    v = fmaxf(v, swz<0x401F>(v));
    return red32_max(v);
}

// ---- merged: weight pre-split + att fp16 tables + graph bounds + hist zero
//      + pad-table prefill (pad[i][j] = i, valid index for slots >= deg) ----
__global__ __launch_bounds__(256) void k_prep(
        const float* __restrict__ Wl0, const float* __restrict__ Wr0, const float* __restrict__ Rw0,
        const float* __restrict__ Wl1, const float* __restrict__ Wr1, const float* __restrict__ Rw1,
        const float* __restrict__ Wl2, const float* __restrict__ Wr2, const float* __restrict__ Rw2,
        const float* __restrict__ att0, const float* __restrict__ att1, const float* __restrict__ att2,
        short* __restrict__ Ws0, short* __restrict__ Ws1, short* __restrict__ Ws2,
        _Float16* __restrict__ attp,
        const int* __restrict__ batch,
        int* __restrict__ startg, int* __restrict__ endg,
        int* __restrict__ cnt8, u16* __restrict__ pad) {
    int i = blockIdx.x * 256 + threadIdx.x;
    if (i < 3 * HID) {   // leaky(v)*a = 0.6a*v + 0.4a*|v|; pre-scale in fp16
        int L = i >> 6, c = i & 63;
        const float* at = (L == 0) ? att0 : (L == 1) ? att1 : att2;
        float a = at[c];
        attp[L * 2 * HID + c] = (_Float16)(0.6f * a);
        attp[L * 2 * HID + HID + c] = (_Float16)(0.4f * a);
    }
    if (i < NN) {        // graph bounds (race-free: each entry has one writer)
#pragma unroll
        for (int g = 0; g < 8; g++) cnt8[g * NN + i] = 0;
        unsigned pv = (unsigned)i | ((unsigned)i << 16);
        unsigned* pp = (unsigned*)&pad[(size_t)i * 32];
#pragma unroll
        for (int j = 0; j < 16; j++) pp[j] = pv;       // prefill self-index
        int g = batch[i];
        if (i == 0) {
            startg[g] = 0;
            for (int g2 = 0; g2 < g; g2++) { startg[g2] = 0; endg[g2] = 0; }
        } else if (batch[i - 1] != g) {
            startg[g] = i;
            for (int g2 = batch[i - 1] + 1; g2 < g; g2++) { startg[g2] = i; endg[g2] = i; }
        }
        if (i == NN - 1) {
            endg[g] = NN;
            for (int g2 = g + 1; g2 < NG; g2++) { startg[g2] = NN; endg[g2] = NN; }
        } else if (batch[i + 1] != g) {
            endg[g] = i + 1;
        }
    }
    const int L0N = 3 * HID * DIN0;
    const int L1N = 3 * HID * HID;
    if (i >= L0N + 2 * L1N) return;
    const float* Wm; short* Ws; int din, local;
    if (i < L0N) {
        local = i; din = DIN0; Ws = Ws0;
        int m = local / (DIN0 * HID);
        Wm = (m == 0) ? Wl0 : (m == 1) ? Wr0 : Rw0;
    } else if (i < L0N + L1N) {
        local = i - L0N; din = HID; Ws = Ws1;
        int m = local / (HID * HID);
        Wm = (m == 0) ? Wl1 : (m == 1) ? Wr1 : Rw1;
    } else {
        local = i - L0N - L1N; din = HID; Ws = Ws2;
        int m = local / (HID * HID);
        Wm = (m == 0) ? Wl2 : (m == 1) ? Wr2 : Rw2;
    }
    int m = local / (din * HID);
    int r = local - m * (din * HID);
    int c = r / din, k = r - c * din;
    float w = Wm[c * din + k];
    short hi = split_hi(w);
    short lo = split_lo(w, hi);
    Ws[(((m * 2 + 0) * HID + c) * din) + k] = hi;
    Ws[(((m * 2 + 1) * HID + c) * din) + k] = lo;
}

// ---- shared gemm body: split-precision bf16 MFMA; xl,xr output as fp16 ----
template <int DIN, bool RELU>
__device__ __forceinline__ void gemm_body(
        int nb0, const float* __restrict__ xin, const short* __restrict__ Ws,
        const float* __restrict__ bvec, const float* __restrict__ rb,
        _Float16* __restrict__ xl16, _Float16* __restrict__ xr16, float* __restrict__ acc) {
    constexpr int LROW = 40;
    __shared__ short lds[20480];            // 40 KB
    short* xhi = lds;
    short* xlo = lds + 2560;

    const int tid = threadIdx.x;
    const int w = tid >> 6;
    const int lane = tid & 63;
    const int col = lane & 15;
    const int quad = lane >> 4;

    f32x4 d[3][4];
#pragma unroll
    for (int m = 0; m < 3; m++)
#pragma unroll
        for (int ct = 0; ct < 4; ct++) d[m][ct] = (f32x4){0.f, 0.f, 0.f, 0.f};

    for (int c0 = 0; c0 < DIN; c0 += 32) {
        if (c0) __syncthreads();
        for (int u = tid; u < 512; u += 256) {
            int row = u >> 3, kq = u & 7;
            int n = nb0 + row;
            float4 v = make_float4(0.f, 0.f, 0.f, 0.f);
            if (n < NN) {
                v = *(const float4*)&xin[(size_t)n * DIN + c0 + 4 * kq];
                if (RELU) {
                    v.x = fmaxf(v.x, 0.f); v.y = fmaxf(v.y, 0.f);
                    v.z = fmaxf(v.z, 0.f); v.w = fmaxf(v.w, 0.f);
                }
            }
            s4v h, l;
            short h0 = split_hi(v.x), l0 = split_lo(v.x, h0);
            short h1 = split_hi(v.y), l1 = split_lo(v.y, h1);
            short h2 = split_hi(v.z), l2 = split_lo(v.z, h2);
            short h3 = split_hi(v.w), l3 = split_lo(v.w, h3);
            h[0] = h0; h[1] = h1; h[2] = h2; h[3] = h3;
            l[0] = l0; l[1] = l1; l[2] = l2; l[3] = l3;
            *(s4v*)&xhi[row * LROW + 4 * kq] = h;
            *(s4v*)&xlo[row * LROW + 4 * kq] = l;
        }
        for (int u = tid; u < 1536; u += 256) {
            int mp = u >> 8;
            int r = u & 255;
            int c = r >> 2, q = r & 3;
            s8v v = *(const s8v*)&Ws[((mp * HID + c) * DIN) + c0 + 8 * q];
            *(s8v*)&lds[5120 + mp * 2560 + c * LROW + 8 * q] = v;
        }
        __syncthreads();

        bf16x8 a_h = __builtin_bit_cast(bf16x8,
            *(const s8v*)&xhi[(w * 16 + col) * LROW + quad * 8]);
        bf16x8 a_l = __builtin_bit_cast(bf16x8,
            *(const s8v*)&xlo[(w * 16 + col) * LROW + quad * 8]);

#pragma unroll
        for (int m = 0; m < 3; m++) {
#pragma unroll
            for (int ct = 0; ct < 4; ct++) {
                bf16x8 b_h = __builtin_bit_cast(bf16x8,
                    *(const s8v*)&lds[5120 + (m * 2 + 0) * 2560 + (ct * 16 + col) * LROW + quad * 8]);
                bf16x8 b_l = __builtin_bit_cast(bf16x8,
                    *(const s8v*)&lds[5120 + (m * 2 + 1) * 2560 + (ct * 16 + col) * LROW + quad * 8]);
                d[m][ct] = __builtin_amdgcn_mfma_f32_16x16x32_bf16(a_h, b_h, d[m][ct], 0, 0, 0);
                d[m][ct] = __builtin_amdgcn_mfma_f32_16x16x32_bf16(a_h, b_l, d[m][ct], 0, 0, 0);
                d[m][ct] = __builtin_amdgcn_mfma_f32_16x16x32_bf16(a_l, b_h, d[m][ct], 0, 0, 0);
            }
        }
    }

#pragma unroll
    for (int r = 0; r < 4; r++) {
        int n = nb0 + w * 16 + quad * 4 + r;
        if (n >= NN) continue;
        size_t base = (size_t)n * HID;
#pragma unroll
        for (int ct = 0; ct < 4; ct++) {
            int c = ct * 16 + col;
            xl16[base + c] = (_Float16)d[0][ct][r];
            xr16[base + c] = (_Float16)d[1][ct][r];
            acc[base + c] = d[2][ct][r] + bvec[c] + rb[c];
        }
    }
}

// ---- fused: gemm L0 (blocks [0,G0B)) + XCD-sliced histogram (blocks [G0B,G0B+HB)) ----
__global__ __launch_bounds__(256, 3) void k_g0_hist(
        const float* __restrict__ xin, const short* __restrict__ Ws,
        const float* __restrict__ bvec, const float* __restrict__ rb,
        _Float16* __restrict__ xl16, _Float16* __restrict__ xr16, float* __restrict__ acc,
        const int* __restrict__ edst, int* __restrict__ cnt8, u16* __restrict__ rank) {
    if (blockIdx.x < G0B) {
        gemm_body<DIN0, false>(blockIdx.x * 64, xin, Ws, bvec, rb, xl16, xr16, acc);
    } else {
        int b = blockIdx.x - G0B;
        int* mycnt = cnt8 + (b & 7) * NN;
        for (int e = b * 256 + threadIdx.x; e < NE; e += HB * 256) {
            int r = atomicAdd(&mycnt[edst[e]], 1);
            rank[e] = (u16)r;
        }
    }
}

// ---- standalone gemm (layers 1,2) ----
template <int DIN, bool RELU>
__global__ __launch_bounds__(256, 3) void k_gemm(
        const float* __restrict__ xin, const short* __restrict__ Ws,
        const float* __restrict__ bvec, const float* __restrict__ rb,
        _Float16* __restrict__ xl16, _Float16* __restrict__ xr16, float* __restrict__ acc) {
    gemm_body<DIN, RELU>(blockIdx.x * 64, xin, Ws, bvec, rb, xl16, xr16, acc);
}

// ---- merged: per-dst slice prefixes (in place) + chunk partial sums ----
// prefixes start at 1 - slot 0 of each dst is the self-loop edge.
__global__ __launch_bounds__(256) void k_histscan(int* __restrict__ cnt8,
                                                  int* __restrict__ cnt,
                                                  int* __restrict__ part) {
    __shared__ int ws[4];
    int b = blockIdx.x, t = threadIdx.x;
    int i0 = b * SCHUNK + t * 4;
    int tot = 0;
#pragma unroll
    for (int j = 0; j < 4; j++) {
        int i = i0 + j;
        if (i < NN) {
            int s = 1;                       // reserve slot 0 for self-loop
#pragma unroll
            for (int g = 0; g < 8; g++) {
                int v = cnt8[g * NN + i];
                cnt8[g * NN + i] = s;
                s += v;
            }
            cnt[i] = s;                      // deg + 1 (incl self)
            tot += s;
        }
    }
#pragma unroll
    for (int o = 32; o; o >>= 1) tot += __shfl_xor(tot, o, 64);
    if ((t & 63) == 0) ws[t >> 6] = tot;
    __syncthreads();
    if (t == 0) part[b] = ws[0] + ws[1] + ws[2] + ws[3];
}

// ---- scan emit (block base computed inline from part[]); also writes the
// self-loop src (srcs[off[i]] = i) - runs before scatter. ----
__global__ __launch_bounds__(256) void k_scan_emit(const int* __restrict__ cnt,
                                                   const int* __restrict__ part,
                                                   int* __restrict__ off,
                                                   u16* __restrict__ srcs) {
    __shared__ int tsum[256];
    __shared__ int baseSh;
    int b = blockIdx.x, t = threadIdx.x;
    if (t < 64) {                            // SNB=49 <= 64
        int v = (t < b && t < SNB) ? part[t] : 0;
#pragma unroll
        for (int o = 32; o; o >>= 1) v += __shfl_xor(v, o, 64);
        if (t == 0) baseSh = v;
    }
    int i0 = b * SCHUNK + t * 4;
    int e[4], p[4];
    int s = 0;
#pragma unroll
    for (int j = 0; j < 4; j++) {
        int i = i0 + j;
        e[j] = (i < NN) ? cnt[i] : 0;
        p[j] = s;
        s += e[j];
    }
    tsum[t] = s;
    __syncthreads();
    for (int d = 1; d < 256; d <<= 1) {
        int v = (t >= d) ? tsum[t - d] : 0;
        __syncthreads();
        tsum[t] += v;
        __syncthreads();
    }
    int base = baseSh + ((t == 0) ? 0 : tsum[t - 1]);
#pragma unroll
    for (int j = 0; j < 4; j++) {
        int i = i0 + j;
        if (i < NN) {
            int v = base + p[j];
            off[i] = v;
            srcs[v] = (u16)i;                // self-loop edge in slot 0
            if (i == NN - 1) off[NN] = v + e[j];
        }
    }
}

// ---- atomic-free scatter: pos = off[d] + sliceBase[slice][d] + rank[e];
//      dual-writes the padded chunk-0 table for slots < 32 ----
__global__ __launch_bounds__(256) void k_scatter_rank(
        const int* __restrict__ esrc, const int* __restrict__ edst,
        const int* __restrict__ off, const int* __restrict__ cnt8,
        const u16* __restrict__ rank, u16* __restrict__ srcs,
        u16* __restrict__ pad) {
    int e = blockIdx.x * 256 + threadIdx.x;
    if (e >= NE) return;
    int d = edst[e];
    int slice = (e >> 8) & 7;               // matches k_g0_hist's block mapping
    int rp = cnt8[slice * NN + d] + (int)rank[e];   // slot within dst (>=1)
    srcs[off[d] + rp] = (u16)esrc[e];
    if (rp < 32) pad[(size_t)d * 32 + rp] = (u16)esrc[e];
}

// ---- fused per-dst attention: 2 dsts/wave, 8 gathers in flight,
//      per-dst slot-2/3 gating; chunk-0 srcs from pad (no off dependency) ----
__global__ __launch_bounds__(256) void k_attn_dst(
        const int* __restrict__ off, const u16* __restrict__ srcs,
        const u16* __restrict__ pad,
        const _Float16* __restrict__ xl16, const _Float16* __restrict__ xr16,
        const _Float16* __restrict__ attL, float* __restrict__ acc) {
    const int lane = threadIdx.x & 63;
    const int d0 = blockIdx.x * 8 + (threadIdx.x >> 6) * 2;   // NN%8==0: always valid
    const int d1 = d0 + 1;
    const int e = lane >> 3;
    const int cg = lane & 7;

    // chunk-0 srcs: depend only on d0/d1 - issue before off loads
    const u16* p0 = &pad[(size_t)d0 * 32];
    const u16* p1 = &pad[(size_t)d1 * 32];
    int s00 = (int)p0[e];
    int s01 = (int)p0[8 + e];
    int s02 = (int)p0[16 + e];
    int s03 = (int)p0[24 + e];
    int s10 = (int)p1[e];
    int s11 = (int)p1[8 + e];
    int s12 = (int)p1[16 + e];
    int s13 = (int)p1[24 + e];

    const int lo0 = off[d0], deg0 = off[d0 + 1] - lo0;
    const int lo1 = off[d1], deg1 = off[d1 + 1] - lo1;

    uint4 X0 = *(const uint4*)&xr16[(size_t)d0 * HID + 8 * cg];
    uint4 X1 = *(const uint4*)&xr16[(size_t)d1 * HID + 8 * cg];
    uint4 A6 = *(const uint4*)&attL[8 * cg];
    uint4 A4 = *(const uint4*)&attL[HID + 8 * cg];
    h2v x00 = u2h(X0.x), x01 = u2h(X0.y), x02 = u2h(X0.z), x03 = u2h(X0.w);
    h2v x10 = u2h(X1.x), x11 = u2h(X1.y), x12 = u2h(X1.z), x13 = u2h(X1.w);
    h2v a60 = u2h(A6.x), a61 = u2h(A6.y), a62 = u2h(A6.z), a63 = u2h(A6.w);
    h2v a40 = u2h(A4.x), a41 = u2h(A4.y), a42 = u2h(A4.z), a43 = u2h(A4.w);

#define GATHER(S) (*(const uint4*)&xl16[(size_t)(S) * HID + 8 * cg])
#define LOGIT(U, XH0, XH1, XH2, XH3, T)                                        \
    {                                                                          \
        h2v _v; unsigned _a; float _q0, _q1;                                   \
        _v = u2h(U.x) + XH0; _a = h2u(_v) & 0x7FFF7FFFu;                       \
        _q0 = __builtin_amdgcn_fdot2(a60, _v, 0.f, false);                     \
        _q1 = __builtin_amdgcn_fdot2(a40, u2h(_a), 0.f, false);                \
        _v = u2h(U.y) + XH1; _a = h2u(_v) & 0x7FFF7FFFu;                       \
        _q0 = __builtin_amdgcn_fdot2(a61, _v, _q0, false);                     \
        _q1 = __builtin_amdgcn_fdot2(a41, u2h(_a), _q1, false);                \
        _v = u2h(U.z) + XH2; _a = h2u(_v) & 0x7FFF7FFFu;                       \
        _q0 = __builtin_amdgcn_fdot2(a62, _v, _q0, false);                     \
        _q1 = __builtin_amdgcn_fdot2(a42, u2h(_a), _q1, false);                \
        _v = u2h(U.w) + XH3; _a = h2u(_v) & 0x7FFF7FFFu;                       \
        _q0 = __builtin_amdgcn_fdot2(a63, _v, _q0, false);                     \
        _q1 = __builtin_amdgcn_fdot2(a43, u2h(_a), _q1, false);                \
        T = octet_sum(_q0 + _q1);                                              \
    }
#define PVACC(P, Ua, Ub, OA, OB)                                               \
    OA.x = __builtin_amdgcn_fdot2(P, pklo(Ua.x, Ub.x), OA.x, false);           \
    OA.y = __builtin_amdgcn_fdot2(P, pkhi(Ua.x, Ub.x), OA.y, false);           \
    OA.z = __builtin_amdgcn_fdot2(P, pklo(Ua.y, Ub.y), OA.z, false);           \
    OA.w = __builtin_amdgcn_fdot2(P, pkhi(Ua.y, Ub.y), OA.w, false);           \
    OB.x = __builtin_amdgcn_fdot2(P, pklo(Ua.z, Ub.z), OB.x, false);           \
    OB.y = __builtin_amdgcn_fdot2(P, pkhi(Ua.z, Ub.z), OB.y, false);           \
    OB.z = __builtin_amdgcn_fdot2(P, pklo(Ua.w, Ub.w), OB.z, false);           \
    OB.w = __builtin_amdgcn_fdot2(P, pkhi(Ua.w, Ub.w), OB.w, false);

    const bool a2 = deg0 > 16, a3 = deg0 > 24;      // wave-uniform, per-dst
    const bool b2 = deg1 > 16, b3 = deg1 > 24;

    uint4 U00 = GATHER(s00), U01 = GATHER(s01);
    uint4 U10 = GATHER(s10), U11 = GATHER(s11);
    uint4 U02, U03, U12, U13;
    float t00, t01, t02 = -INFINITY, t03 = -INFINITY;
    float t10, t11, t12 = -INFINITY, t13 = -INFINITY;
    if (a2) {
        U02 = GATHER(s02);
        if (a3) U03 = GATHER(s03); else U03 = U00;   // valid bits; p3 will be 0
    }
    if (b2) {
        U12 = GATHER(s12);
        if (b3) U13 = GATHER(s13); else U13 = U10;
    }
    LOGIT(U00, x00, x01, x02, x03, t00);
    LOGIT(U01, x00, x01, x02, x03, t01);
    LOGIT(U10, x10, x11, x12, x13, t10);
    LOGIT(U11, x10, x11, x12, x13, t11);
    if (e >= deg0) t00 = -INFINITY;
    if (8 + e >= deg0) t01 = -INFINITY;
    if (e >= deg1) t10 = -INFINITY;
    if (8 + e >= deg1) t11 = -INFINITY;
    if (a2) {
        LOGIT(U02, x00, x01, x02, x03, t02);
        if (16 + e >= deg0) t02 = -INFINITY;
        if (a3) {
            LOGIT(U03, x00, x01, x02, x03, t03);
            if (24 + e >= deg0) t03 = -INFINITY;
        }
    }
    if (b2) {
        LOGIT(U12, x10, x11, x12, x13, t12);
        if (16 + e >= deg1) t12 = -INFINITY;
        if (b3) {
            LOGIT(U13, x10, x11, x12, x13, t13);
            if (24 + e >= deg1) t13 = -INFINITY;
        }
    }

    float m0 = emax(fmaxf(fmaxf(t00, t01), fmaxf(t02, t03)));
    float m1 = emax(fmaxf(fmaxf(t10, t11), fmaxf(t12, t13)));

    float p00 = __expf(t00 - m0), p01 = __expf(t01 - m0);
    float p10 = __expf(t10 - m1), p11 = __expf(t11 - m1);
    float l0 = p00 + p01, l1 = p10 + p11;
    float4 oA0 = make_float4(0.f, 0.f, 0.f, 0.f), oB0 = oA0;
    float4 oA1 = oA0, oB1 = oA0;
    {
        h2v pa = {(_Float16)p00, (_Float16)p01};
        h2v pb = {(_Float16)p10, (_Float16)p11};
        PVACC(pa, U00, U01, oA0, oB0)
        PVACC(pb, U10, U11, oA1, oB1)
    }
    if (a2) {
        float p02 = __expf(t02 - m0), p03 = __expf(t03 - m0);
        l0 += p02 + p03;
        h2v pa = {(_Float16)p02, (_Float16)p03};
        PVACC(pa, U02, U03, oA0, oB0)
    }
    if (b2) {
        float p12 = __expf(t12 - m1), p13 = __expf(t13 - m1);
        l1 += p12 + p13;
        h2v pb = {(_Float16)p12, (_Float16)p13};
        PVACC(pb, U12, U13, oA1, oB1)
    }

    // ---- continuation (rare, deg > 32): general online-softmax body ----
#define GENLOOP(LO, DEG, XH0, XH1, XH2, XH3, M, L, OA, OB)                     \
    for (int base = 32; base < DEG; base += 32) {                              \
        const int rem = DEG - base;                                            \
        int s0 = (int)srcs[LO + min(base + e, DEG - 1)];                       \
        int s1 = (int)srcs[LO + min(base + 8 + e, DEG - 1)];                   \
        int s2 = (int)srcs[LO + min(base + 16 + e, DEG - 1)];                  \
        int s3 = (int)srcs[LO + min(base + 24 + e, DEG - 1)];                  \
        uint4 V0 = GATHER(s0), V1 = GATHER(s1), V2, V3;                        \
        float u0, u1, u2 = -INFINITY, u3 = -INFINITY;                          \
        LOGIT(V0, XH0, XH1, XH2, XH3, u0);                                     \
        LOGIT(V1, XH0, XH1, XH2, XH3, u1);                                     \
        if (base + e >= DEG) u0 = -INFINITY;                                   \
        if (base + 8 + e >= DEG) u1 = -INFINITY;                               \
        const bool c2 = rem > 16;                                              \
        if (c2) {                                                              \
            V2 = GATHER(s2);                                                   \
            LOGIT(V2, XH0, XH1, XH2, XH3, u2);                                 \
            if (base + 16 + e >= DEG) u2 = -INFINITY;                          \
            if (rem > 24) {                                                    \
                V3 = GATHER(s3);                                               \
                LOGIT(V3, XH0, XH1, XH2, XH3, u3);                             \
                if (base + 24 + e >= DEG) u3 = -INFINITY;                      \
            } else { V3 = V0; }                                                \
        }                                                                      \
        float cm = emax(fmaxf(fmaxf(u0, u1), fmaxf(u2, u3)));                  \
        if (cm > M) {                                                          \
            float corr = __expf(M - cm);                                       \
            M = cm;                                                            \
            L *= corr;                                                         \
            OA.x *= corr; OA.y *= corr; OA.z *= corr; OA.w *= corr;            \
            OB.x *= corr; OB.y *= corr; OB.z *= corr; OB.w *= corr;            \
        }                                                                      \
        float q0 = __expf(u0 - M), q1 = __expf(u1 - M);                        \
        L += q0 + q1;                                                          \
        h2v qp = {(_Float16)q0, (_Float16)q1};                                 \
        PVACC(qp, V0, V1, OA, OB)                                              \
        if (c2) {                                                              \
            float q2 = __expf(u2 - M), q3 = __expf(u3 - M);                    \
            L += q2 + q3;                                                      \
            h2v qq = {(_Float16)q2, (_Float16)q3};                             \
            PVACC(qq, V2, V3, OA, OB)                                          \
        }                                                                      \
    }

    if (deg0 > 32) { GENLOOP(lo0, deg0, x00, x01, x02, x03, m0, l0, oA0, oB0) }
    if (deg1 > 32) { GENLOOP(lo1, deg1, x10, x11, x12, x13, m1, l1, oA1, oB1) }
#undef GENLOOP
#undef GATHER
#undef LOGIT
#undef PVACC

    // ---- epilogue: interleaved reduces, parallel write (e=0 -> d0, e=1 -> d1)
    l0    = esum(l0);    l1    = esum(l1);
    oA0.x = esum(oA0.x); oA1.x = esum(oA1.x);
    oA0.y = esum(oA0.y); oA1.y = esum(oA1.y);
    oA0.z = esum(oA0.z); oA1.z = esum(oA1.z);
    oA0.w = esum(oA0.w); oA1.w = esum(oA1.w);
    oB0.x = esum(oB0.x); oB1.x = esum(oB1.x);
    oB0.y = esum(oB0.y); oB1.y = esum(oB1.y);
    oB0.z = esum(oB0.z); oB1.z = esum(oB1.z);
    oB0.w = esum(oB0.w); oB1.w = esum(oB1.w);

    if (e < 2) {
        const bool s = (e == 1);
        int dd = s ? d1 : d0;
        float inv = 1.f / (s ? l1 : l0);
        float4 wA = s ? oA1 : oA0;
        float4 wB = s ? oB1 : oB0;
        float4* a4 = (float4*)&acc[(size_t)dd * HID + 8 * cg];
        float4 c0 = a4[0], c1 = a4[1];
        c0.x += wA.x * inv; c0.y += wA.y * inv;
        c0.z += wA.z * inv; c0.w += wA.w * inv;
        c1.x += wB.x * inv; c1.y += wB.y * inv;
        c1.z += wB.z * inv; c1.w += wB.w * inv;
        a4[0] = c0; a4[1] = c1;
    }
}

// ---- fused mean-pool + head ----
__global__ __launch_bounds__(512) void k_pool_final(
        const float* __restrict__ acc,
        const int* __restrict__ startg, const int* __restrict__ endg,
        const float* __restrict__ Wf, const float* __restrict__ bf_,
        float* __restrict__ out) {
    __shared__ float red[8][HID];
    const int g = blockIdx.x;
    const int c = threadIdx.x & 63;
    const int j = threadIdx.x >> 6;
    const int s = startg[g], epos = endg[g];

    float sum = 0.f;
    for (int n = s + j; n < epos; n += 8)
        sum += acc[(size_t)n * HID + c];
    red[j][c] = sum;
    __syncthreads();

    if (threadIdx.x < HID) {
        float tot = 0.f;
#pragma unroll
        for (int w = 0; w < 8; w++) tot += red[w][c];
        float cntf = (float)(epos - s);
        float v = tot / fmaxf(cntf, 1.f) * Wf[c];
#pragma unroll
        for (int o = 32; o; o >>= 1) v += __shfl_xor(v, o, 64);
        if (c == 0) out[g] = v + bf_[0];
    }
}

extern "C" void kernel_launch(void* const* d_in, const int* in_sizes, int n_in,
                              void* d_out, int out_size, void* d_ws, size_t ws_size,
                              hipStream_t stream) {
    const float* x   = (const float*)d_in[0];
    const int* eidx  = (const int*)d_in[1];
    const int* batch = (const int*)d_in[2];
    const int* esrc = eidx;
    const int* edst = eidx + NE;
    const float* Wf  = (const float*)d_in[21];
    const float* bfb = (const float*)d_in[22];

    float* wsf = (float*)d_ws;
    const size_t NN64 = (size_t)NN * HID;
    _Float16* xl16 = (_Float16*)wsf;                // NN64 halfs (slot: NN64 floats)
    _Float16* xr16 = (_Float16*)(wsf + NN64);       // NN64 halfs
    float* acc0   = wsf + 2 * NN64;
    float* acc1   = acc0 + NN64;
    short* Ws0    = (short*)(acc1 + NN64);
    short* Ws1    = Ws0 + 2 * 3 * HID * DIN0;
    short* Ws2    = Ws1 + 2 * 3 * HID * HID;
    int*   ccnt   = (int*)(Ws2 + 2 * 3 * HID * HID);
    int*   startg = ccnt + NN;
    int*   endg   = startg + NG;
    int*   off    = endg + NG;
    int*   part   = off + NN + 1;
    int*   partSc = part + SNB;
    int*   cnt8   = partSc + SNB;                   // 8*NN
    u16*   rank   = (u16*)(cnt8 + 8 * NN);          // NE u16
    u16*   srcs   = rank + NE;                      // NE + NN u16 (self-loops)
    _Float16* attp = (_Float16*)(srcs + NE + NN);   // 3 * 2*HID halfs
    u16*   pad    = (u16*)(attp + 3 * 2 * HID);     // NN * 32 u16 (3.2 MB)

    k_prep<<<(NN + 255) / 256, 256, 0, stream>>>(
        (const float*)d_in[3], (const float*)d_in[4], (const float*)d_in[7],
        (const float*)d_in[9], (const float*)d_in[10], (const float*)d_in[13],
        (const float*)d_in[15], (const float*)d_in[16], (const float*)d_in[19],
        (const float*)d_in[5], (const float*)d_in[11], (const float*)d_in[17],
        Ws0, Ws1, Ws2, attp, batch, startg, endg, cnt8, pad);

    // fused: gemm L0 (independent of edges) || hist8 (independent of gemm)
    k_g0_hist<<<G0B + HB, 256, 0, stream>>>(
        x, Ws0, (const float*)d_in[6], (const float*)d_in[8],
        xl16, xr16, acc0, edst, cnt8, rank);

    k_histscan<<<SNB, 256, 0, stream>>>(cnt8, ccnt, part);
    k_scan_emit<<<SNB, 256, 0, stream>>>(ccnt, part, off, srcs);
    k_scatter_rank<<<(NE + 255) / 256, 256, 0, stream>>>(esrc, edst, off, cnt8, rank, srcs, pad);

    const short* Wss[3] = {Ws0, Ws1, Ws2};
    float* accs[4] = {acc0, acc0, acc1, acc0};  // out of layer L = accs[L+1]
    const int gemm_grid = (NN + 63) / 64;
    for (int L = 0; L < 3; L++) {
        const float* b   = (const float*)d_in[3 + L * 6 + 3];
        const float* Rb  = (const float*)d_in[3 + L * 6 + 5];
        float* accOut = accs[L + 1];

        if (L > 0)
            k_gemm<HID, true><<<gemm_grid, 256, 0, stream>>>(
                accs[L], Wss[L], b, Rb, xl16, xr16, accOut);

        k_attn_dst<<<NN / 8, 256, 0, stream>>>(
            off, srcs, pad, xl16, xr16, attp + L * 2 * HID, accOut);
    }

    k_pool_final<<<NG, 512, 0, stream>>>(accs[3], startg, endg, Wf, bfb, (float*)d_out);
}

// Round 15
// 295.460 us; speedup vs baseline: 1.0455x; 1.0455x over previous
//
#include <hip/hip_runtime.h>

// GATv2 3-layer + mean-pool + linear head, MI355X.
// R34 = R32 verbatim (session best, 295.8us). R33's pad-table REGRESSED
// (308.9): prep prefill (3.2MB) + scatter dual-write + pad reads cost more
// than the removed off->srcs chain level. All levers now bracketed:
// attn ILP (1<2>4 dst/wave, persistent worse), g0+hist schedule (serial 48us
// < interleaved 60us), VALU/LGKM diets captured, chain-shortening regressed.
// 369.8 -> 295.8us across the session (-20%).

#define NN 50000
#define NE 1000000
#define HID 64
#define DIN0 128
#define NG 256
#define NEG 0.2f

#define SCHUNK 1024
#define SNB ((NN + SCHUNK - 1) / SCHUNK)   // 49 blocks
#define G0B ((NN + 63) / 64)               // 782 gemm-L0 blocks
#define HB 512                             // hist8 blocks

typedef float f32x4 __attribute__((ext_vector_type(4)));
typedef short s8v __attribute__((ext_vector_type(8)));
typedef short s4v __attribute__((ext_vector_type(4)));
typedef __bf16 bf16x8 __attribute__((ext_vector_type(8)));
typedef _Float16 h2v __attribute__((ext_vector_type(2)));
typedef unsigned u32x2 __attribute__((ext_vector_type(2)));
typedef unsigned short u16;

__device__ __forceinline__ unsigned short f2bf(float f) {
    unsigned u = __float_as_uint(f);
    u = u + 0x7fffu + ((u >> 16) & 1u);   // RNE
    return (unsigned short)(u >> 16);
}
__device__ __forceinline__ float bf2f(unsigned short v) {
    return __uint_as_float(((unsigned)v) << 16);
}
__device__ __forceinline__ short split_hi(float x) {
    return (short)f2bf(x);
}
__device__ __forceinline__ short split_lo(float x, short hi) {
    return (short)f2bf(x - bf2f((unsigned short)hi));
}
__device__ __forceinline__ h2v u2h(unsigned u) { return __builtin_bit_cast(h2v, u); }
__device__ __forceinline__ unsigned h2u(h2v h) { return __builtin_bit_cast(unsigned, h); }
// (b.lo16 << 16) | a.lo16  and  (b.hi16 << 16) | a.hi16  - one v_perm_b32 each
__device__ __forceinline__ h2v pklo(unsigned a, unsigned b) {
    return u2h(__builtin_amdgcn_perm(b, a, 0x05040100u));
}
__device__ __forceinline__ h2v pkhi(unsigned a, unsigned b) {
    return u2h(__builtin_amdgcn_perm(b, a, 0x07060302u));
}
// cross-lane primitives on the VALU pipe (DPP / permlane) + ds_swizzle
template <int CTRL>
__device__ __forceinline__ float dpp_mv(float v) {   // value from lane per CTRL
    return __int_as_float(
        __builtin_amdgcn_update_dpp(0, __float_as_int(v), CTRL, 0xF, 0xF, true));
}
template <int OFF>
__device__ __forceinline__ float swz(float v) {      // ds_swizzle xor mode
    return __int_as_float(__builtin_amdgcn_ds_swizzle(__float_as_int(v), OFF));
}
__device__ __forceinline__ float red32_add(float v) {
    unsigned u = __float_as_uint(v);
    u32x2 r = __builtin_amdgcn_permlane32_swap(u, u, false, false);
    return __uint_as_float(r[0]) + __uint_as_float(r[1]);
}
__device__ __forceinline__ float red32_max(float v) {
    unsigned u = __float_as_uint(v);
    u32x2 r = __builtin_amdgcn_permlane32_swap(u, u, false, false);
    return fmaxf(__uint_as_float(r[0]), __uint_as_float(r[1]));
}
// sum over the 8 cg lanes of an octet: xor1(DPP) xor2(DPP) xor4(swizzle)
__device__ __forceinline__ float octet_sum(float v) {
    v += dpp_mv<0xB1>(v);        // quad_perm(1,0,3,2) == xor1
    v += dpp_mv<0x4E>(v);        // quad_perm(2,3,0,1) == xor2
    v += swz<0x101F>(v);         // xor4
    return v;
}
// sum/max over the 8 e-slots: xor8(DPP row_ror:8) xor16(swizzle) xor32(permlane)
__device__ __forceinline__ float esum(float v) {
    v += dpp_mv<0x128>(v);       // row_ror:8 == xor8
    v += swz<0x401F>(v);         // xor16
    return red32_add(v);
}
__device__ __forceinline__ float emax(float v) {
    v = fmaxf(v, dpp_mv<0x128>(v));
    v = fmaxf(v, swz<0x401F>(v));
    return red32_max(v);
}

// ---- merged: weight pre-split + att fp16 tables + graph bounds + hist zero ----
__global__ __launch_bounds__(256) void k_prep(
        const float* __restrict__ Wl0, const float* __restrict__ Wr0, const float* __restrict__ Rw0,
        const float* __restrict__ Wl1, const float* __restrict__ Wr1, const float* __restrict__ Rw1,
        const float* __restrict__ Wl2, const float* __restrict__ Wr2, const float* __restrict__ Rw2,
        const float* __restrict__ att0, const float* __restrict__ att1, const float* __restrict__ att2,
        short* __restrict__ Ws0, short* __restrict__ Ws1, short* __restrict__ Ws2,
        _Float16* __restrict__ attp,
        const int* __restrict__ batch,
        int* __restrict__ startg, int* __restrict__ endg,
        int* __restrict__ cnt8) {
    int i = blockIdx.x * 256 + threadIdx.x;
    if (i < 3 * HID) {   // leaky(v)*a = 0.6a*v + 0.4a*|v|; pre-scale in fp16
        int L = i >> 6, c = i & 63;
        const float* at = (L == 0) ? att0 : (L == 1) ? att1 : att2;
        float a = at[c];
        attp[L * 2 * HID + c] = (_Float16)(0.6f * a);
        attp[L * 2 * HID + HID + c] = (_Float16)(0.4f * a);
    }
    if (i < NN) {        // graph bounds (race-free: each entry has one writer)
#pragma unroll
        for (int g = 0; g < 8; g++) cnt8[g * NN + i] = 0;
        int g = batch[i];
        if (i == 0) {
            startg[g] = 0;
            for (int g2 = 0; g2 < g; g2++) { startg[g2] = 0; endg[g2] = 0; }
        } else if (batch[i - 1] != g) {
            startg[g] = i;
            for (int g2 = batch[i - 1] + 1; g2 < g; g2++) { startg[g2] = i; endg[g2] = i; }
        }
        if (i == NN - 1) {
            endg[g] = NN;
            for (int g2 = g + 1; g2 < NG; g2++) { startg[g2] = NN; endg[g2] = NN; }
        } else if (batch[i + 1] != g) {
            endg[g] = i + 1;
        }
    }
    const int L0N = 3 * HID * DIN0;
    const int L1N = 3 * HID * HID;
    if (i >= L0N + 2 * L1N) return;
    const float* Wm; short* Ws; int din, local;
    if (i < L0N) {
        local = i; din = DIN0; Ws = Ws0;
        int m = local / (DIN0 * HID);
        Wm = (m == 0) ? Wl0 : (m == 1) ? Wr0 : Rw0;
    } else if (i < L0N + L1N) {
        local = i - L0N; din = HID; Ws = Ws1;
        int m = local / (HID * HID);
        Wm = (m == 0) ? Wl1 : (m == 1) ? Wr1 : Rw1;
    } else {
        local = i - L0N - L1N; din = HID; Ws = Ws2;
        int m = local / (HID * HID);
        Wm = (m == 0) ? Wl2 : (m == 1) ? Wr2 : Rw2;
    }
    int m = local / (din * HID);
    int r = local - m * (din * HID);
    int c = r / din, k = r - c * din;
    float w = Wm[c * din + k];
    short hi = split_hi(w);
    short lo = split_lo(w, hi);
    Ws[(((m * 2 + 0) * HID + c) * din) + k] = hi;
    Ws[(((m * 2 + 1) * HID + c) * din) + k] = lo;
}

// ---- shared gemm body: split-precision bf16 MFMA; xl,xr output as fp16 ----
template <int DIN, bool RELU>
__device__ __forceinline__ void gemm_body(
        int nb0, const float* __restrict__ xin, const short* __restrict__ Ws,
        const float* __restrict__ bvec, const float* __restrict__ rb,
        _Float16* __restrict__ xl16, _Float16* __restrict__ xr16, float* __restrict__ acc) {
    constexpr int LROW = 40;
    __shared__ short lds[20480];            // 40 KB
    short* xhi = lds;
    short* xlo = lds + 2560;

    const int tid = threadIdx.x;
    const int w = tid >> 6;
    const int lane = tid & 63;
    const int col = lane & 15;
    const int quad = lane >> 4;

    f32x4 d[3][4];
#pragma unroll
    for (int m = 0; m < 3; m++)
#pragma unroll
        for (int ct = 0; ct < 4; ct++) d[m][ct] = (f32x4){0.f, 0.f, 0.f, 0.f};

    for (int c0 = 0; c0 < DIN; c0 += 32) {
        if (c0) __syncthreads();
        for (int u = tid; u < 512; u += 256) {
            int row = u >> 3, kq = u & 7;
            int n = nb0 + row;
            float4 v = make_float4(0.f, 0.f, 0.f, 0.f);
            if (n < NN) {
                v = *(const float4*)&xin[(size_t)n * DIN + c0 + 4 * kq];
                if (RELU) {
                    v.x = fmaxf(v.x, 0.f); v.y = fmaxf(v.y, 0.f);
                    v.z = fmaxf(v.z, 0.f); v.w = fmaxf(v.w, 0.f);
                }
            }
            s4v h, l;
            short h0 = split_hi(v.x), l0 = split_lo(v.x, h0);
            short h1 = split_hi(v.y), l1 = split_lo(v.y, h1);
            short h2 = split_hi(v.z), l2 = split_lo(v.z, h2);
            short h3 = split_hi(v.w), l3 = split_lo(v.w, h3);
            h[0] = h0; h[1] = h1; h[2] = h2; h[3] = h3;
            l[0] = l0; l[1] = l1; l[2] = l2; l[3] = l3;
            *(s4v*)&xhi[row * LROW + 4 * kq] = h;
            *(s4v*)&xlo[row * LROW + 4 * kq] = l;
        }
        for (int u = tid; u < 1536; u += 256) {
            int mp = u >> 8;
            int r = u & 255;
            int c = r >> 2, q = r & 3;
            s8v v = *(const s8v*)&Ws[((mp * HID + c) * DIN) + c0 + 8 * q];
            *(s8v*)&lds[5120 + mp * 2560 + c * LROW + 8 * q] = v;
        }
        __syncthreads();

        bf16x8 a_h = __builtin_bit_cast(bf16x8,
            *(const s8v*)&xhi[(w * 16 + col) * LROW + quad * 8]);
        bf16x8 a_l = __builtin_bit_cast(bf16x8,
            *(const s8v*)&xlo[(w * 16 + col) * LROW + quad * 8]);

#pragma unroll
        for (int m = 0; m < 3; m++) {
#pragma unroll
            for (int ct = 0; ct < 4; ct++) {
                bf16x8 b_h = __builtin_bit_cast(bf16x8,
                    *(const s8v*)&lds[5120 + (m * 2 + 0) * 2560 + (ct * 16 + col) * LROW + quad * 8]);
                bf16x8 b_l = __builtin_bit_cast(bf16x8,
                    *(const s8v*)&lds[5120 + (m * 2 + 1) * 2560 + (ct * 16 + col) * LROW + quad * 8]);
                d[m][ct] = __builtin_amdgcn_mfma_f32_16x16x32_bf16(a_h, b_h, d[m][ct], 0, 0, 0);
                d[m][ct] = __builtin_amdgcn_mfma_f32_16x16x32_bf16(a_h, b_l, d[m][ct], 0, 0, 0);
                d[m][ct] = __builtin_amdgcn_mfma_f32_16x16x32_bf16(a_l, b_h, d[m][ct], 0, 0, 0);
            }
        }
    }

#pragma unroll
    for (int r = 0; r < 4; r++) {
        int n = nb0 + w * 16 + quad * 4 + r;
        if (n >= NN) continue;
        size_t base = (size_t)n * HID;
#pragma unroll
        for (int ct = 0; ct < 4; ct++) {
            int c = ct * 16 + col;
            xl16[base + c] = (_Float16)d[0][ct][r];
            xr16[base + c] = (_Float16)d[1][ct][r];
            acc[base + c] = d[2][ct][r] + bvec[c] + rb[c];
        }
    }
}

// ---- fused: gemm L0 (blocks [0,G0B)) + XCD-sliced histogram (blocks [G0B,G0B+HB)) ----
__global__ __launch_bounds__(256, 3) void k_g0_hist(
        const float* __restrict__ xin, const short* __restrict__ Ws,
        const float* __restrict__ bvec, const float* __restrict__ rb,
        _Float16* __restrict__ xl16, _Float16* __restrict__ xr16, float* __restrict__ acc,
        const int* __restrict__ edst, int* __restrict__ cnt8, u16* __restrict__ rank) {
    if (blockIdx.x < G0B) {
        gemm_body<DIN0, false>(blockIdx.x * 64, xin, Ws, bvec, rb, xl16, xr16, acc);
    } else {
        int b = blockIdx.x - G0B;
        int* mycnt = cnt8 + (b & 7) * NN;
        for (int e = b * 256 + threadIdx.x; e < NE; e += HB * 256) {
            int r = atomicAdd(&mycnt[edst[e]], 1);
            rank[e] = (u16)r;
        }
    }
}

// ---- standalone gemm (layers 1,2) ----
template <int DIN, bool RELU>
__global__ __launch_bounds__(256, 3) void k_gemm(
        const float* __restrict__ xin, const short* __restrict__ Ws,
        const float* __restrict__ bvec, const float* __restrict__ rb,
        _Float16* __restrict__ xl16, _Float16* __restrict__ xr16, float* __restrict__ acc) {
    gemm_body<DIN, RELU>(blockIdx.x * 64, xin, Ws, bvec, rb, xl16, xr16, acc);
}

// ---- merged: per-dst slice prefixes (in place) + chunk partial sums ----
// prefixes start at 1 - slot 0 of each dst is the self-loop edge.
__global__ __launch_bounds__(256) void k_histscan(int* __restrict__ cnt8,
                                                  int* __restrict__ cnt,
                                                  int* __restrict__ part) {
    __shared__ int ws[4];
    int b = blockIdx.x, t = threadIdx.x;
    int i0 = b * SCHUNK + t * 4;
    int tot = 0;
#pragma unroll
    for (int j = 0; j < 4; j++) {
        int i = i0 + j;
        if (i < NN) {
            int s = 1;                       // reserve slot 0 for self-loop
#pragma unroll
            for (int g = 0; g < 8; g++) {
                int v = cnt8[g * NN + i];
                cnt8[g * NN + i] = s;
                s += v;
            }
            cnt[i] = s;                      // deg + 1 (incl self)
            tot += s;
        }
    }
#pragma unroll
    for (int o = 32; o; o >>= 1) tot += __shfl_xor(tot, o, 64);
    if ((t & 63) == 0) ws[t >> 6] = tot;
    __syncthreads();
    if (t == 0) part[b] = ws[0] + ws[1] + ws[2] + ws[3];
}

// ---- scan emit (block base computed inline from part[]); also writes the
// self-loop src (srcs[off[i]] = i) - runs before scatter. ----
__global__ __launch_bounds__(256) void k_scan_emit(const int* __restrict__ cnt,
                                                   const int* __restrict__ part,
                                                   int* __restrict__ off,
                                                   u16* __restrict__ srcs) {
    __shared__ int tsum[256];
    __shared__ int baseSh;
    int b = blockIdx.x, t = threadIdx.x;
    if (t < 64) {                            // SNB=49 <= 64
        int v = (t < b && t < SNB) ? part[t] : 0;
#pragma unroll
        for (int o = 32; o; o >>= 1) v += __shfl_xor(v, o, 64);
        if (t == 0) baseSh = v;
    }
    int i0 = b * SCHUNK + t * 4;
    int e[4], p[4];
    int s = 0;
#pragma unroll
    for (int j = 0; j < 4; j++) {
        int i = i0 + j;
        e[j] = (i < NN) ? cnt[i] : 0;
        p[j] = s;
        s += e[j];
    }
    tsum[t] = s;
    __syncthreads();
    for (int d = 1; d < 256; d <<= 1) {
        int v = (t >= d) ? tsum[t - d] : 0;
        __syncthreads();
        tsum[t] += v;
        __syncthreads();
    }
    int base = baseSh + ((t == 0) ? 0 : tsum[t - 1]);
#pragma unroll
    for (int j = 0; j < 4; j++) {
        int i = i0 + j;
        if (i < NN) {
            int v = base + p[j];
            off[i] = v;
            srcs[v] = (u16)i;                // self-loop edge in slot 0
            if (i == NN - 1) off[NN] = v + e[j];
        }
    }
}

// ---- atomic-free scatter: pos = off[d] + sliceBase[slice][d] + rank[e] ----
__global__ __launch_bounds__(256) void k_scatter_rank(
        const int* __restrict__ esrc, const int* __restrict__ edst,
        const int* __restrict__ off, const int* __restrict__ cnt8,
        const u16* __restrict__ rank, u16* __restrict__ srcs) {
    int e = blockIdx.x * 256 + threadIdx.x;
    if (e >= NE) return;
    int d = edst[e];
    int slice = (e >> 8) & 7;               // matches k_g0_hist's block mapping
    int pos = off[d] + cnt8[slice * NN + d] + (int)rank[e];
    srcs[pos] = (u16)esrc[e];
}

// ---- fused per-dst attention: 2 dsts/wave, 8 gathers in flight,
//      per-dst slot-2/3 gating ----
__global__ __launch_bounds__(256) void k_attn_dst(
        const int* __restrict__ off, const u16* __restrict__ srcs,
        const _Float16* __restrict__ xl16, const _Float16* __restrict__ xr16,
        const _Float16* __restrict__ attL, float* __restrict__ acc) {
    const int lane = threadIdx.x & 63;
    const int d0 = blockIdx.x * 8 + (threadIdx.x >> 6) * 2;   // NN%8==0: always valid
    const int d1 = d0 + 1;
    const int e = lane >> 3;
    const int cg = lane & 7;

    const int lo0 = off[d0], deg0 = off[d0 + 1] - lo0;
    const int lo1 = off[d1], deg1 = off[d1 + 1] - lo1;

    uint4 X0 = *(const uint4*)&xr16[(size_t)d0 * HID + 8 * cg];
    uint4 X1 = *(const uint4*)&xr16[(size_t)d1 * HID + 8 * cg];
    uint4 A6 = *(const uint4*)&attL[8 * cg];
    uint4 A4 = *(const uint4*)&attL[HID + 8 * cg];
    h2v x00 = u2h(X0.x), x01 = u2h(X0.y), x02 = u2h(X0.z), x03 = u2h(X0.w);
    h2v x10 = u2h(X1.x), x11 = u2h(X1.y), x12 = u2h(X1.z), x13 = u2h(X1.w);
    h2v a60 = u2h(A6.x), a61 = u2h(A6.y), a62 = u2h(A6.z), a63 = u2h(A6.w);
    h2v a40 = u2h(A4.x), a41 = u2h(A4.y), a42 = u2h(A4.z), a43 = u2h(A4.w);

#define GATHER(S) (*(const uint4*)&xl16[(size_t)(S) * HID + 8 * cg])
#define LOGIT(U, XH0, XH1, XH2, XH3, T)                                        \
    {                                                                          \
        h2v _v; unsigned _a; float _q0, _q1;                                   \
        _v = u2h(U.x) + XH0; _a = h2u(_v) & 0x7FFF7FFFu;                       \
        _q0 = __builtin_amdgcn_fdot2(a60, _v, 0.f, false);                     \
        _q1 = __builtin_amdgcn_fdot2(a40, u2h(_a), 0.f, false);                \
        _v = u2h(U.y) + XH1; _a = h2u(_v) & 0x7FFF7FFFu;                       \
        _q0 = __builtin_amdgcn_fdot2(a61, _v, _q0, false);                     \
        _q1 = __builtin_amdgcn_fdot2(a41, u2h(_a), _q1, false);                \
        _v = u2h(U.z) + XH2; _a = h2u(_v) & 0x7FFF7FFFu;                       \
        _q0 = __builtin_amdgcn_fdot2(a62, _v, _q0, false);                     \
        _q1 = __builtin_amdgcn_fdot2(a42, u2h(_a), _q1, false);                \
        _v = u2h(U.w) + XH3; _a = h2u(_v) & 0x7FFF7FFFu;                       \
        _q0 = __builtin_amdgcn_fdot2(a63, _v, _q0, false);                     \
        _q1 = __builtin_amdgcn_fdot2(a43, u2h(_a), _q1, false);                \
        T = octet_sum(_q0 + _q1);                                              \
    }
#define PVACC(P, Ua, Ub, OA, OB)                                               \
    OA.x = __builtin_amdgcn_fdot2(P, pklo(Ua.x, Ub.x), OA.x, false);           \
    OA.y = __builtin_amdgcn_fdot2(P, pkhi(Ua.x, Ub.x), OA.y, false);           \
    OA.z = __builtin_amdgcn_fdot2(P, pklo(Ua.y, Ub.y), OA.z, false);           \
    OA.w = __builtin_amdgcn_fdot2(P, pkhi(Ua.y, Ub.y), OA.w, false);           \
    OB.x = __builtin_amdgcn_fdot2(P, pklo(Ua.z, Ub.z), OB.x, false);           \
    OB.y = __builtin_amdgcn_fdot2(P, pkhi(Ua.z, Ub.z), OB.y, false);           \
    OB.z = __builtin_amdgcn_fdot2(P, pklo(Ua.w, Ub.w), OB.z, false);           \
    OB.w = __builtin_amdgcn_fdot2(P, pkhi(Ua.w, Ub.w), OB.w, false);

    // ---- chunk 0 for both dsts: 8 srcs loads, then gathers, then compute ----
    int s00 = (int)srcs[lo0 + min(e, deg0 - 1)];
    int s01 = (int)srcs[lo0 + min(8 + e, deg0 - 1)];
    int s02 = (int)srcs[lo0 + min(16 + e, deg0 - 1)];
    int s03 = (int)srcs[lo0 + min(24 + e, deg0 - 1)];
    int s10 = (int)srcs[lo1 + min(e, deg1 - 1)];
    int s11 = (int)srcs[lo1 + min(8 + e, deg1 - 1)];
    int s12 = (int)srcs[lo1 + min(16 + e, deg1 - 1)];
    int s13 = (int)srcs[lo1 + min(24 + e, deg1 - 1)];
    const bool a2 = deg0 > 16, a3 = deg0 > 24;      // wave-uniform, per-dst
    const bool b2 = deg1 > 16, b3 = deg1 > 24;

    uint4 U00 = GATHER(s00), U01 = GATHER(s01);
    uint4 U10 = GATHER(s10), U11 = GATHER(s11);
    uint4 U02, U03, U12, U13;
    float t00, t01, t02 = -INFINITY, t03 = -INFINITY;
    float t10, t11, t12 = -INFINITY, t13 = -INFINITY;
    if (a2) {
        U02 = GATHER(s02);
        if (a3) U03 = GATHER(s03); else U03 = U00;   // valid bits; p3 will be 0
    }
    if (b2) {
        U12 = GATHER(s12);
        if (b3) U13 = GATHER(s13); else U13 = U10;
    }
    LOGIT(U00, x00, x01, x02, x03, t00);
    LOGIT(U01, x00, x01, x02, x03, t01);
    LOGIT(U10, x10, x11, x12, x13, t10);
    LOGIT(U11, x10, x11, x12, x13, t11);
    if (e >= deg0) t00 = -INFINITY;
    if (8 + e >= deg0) t01 = -INFINITY;
    if (e >= deg1) t10 = -INFINITY;
    if (8 + e >= deg1) t11 = -INFINITY;
    if (a2) {
        LOGIT(U02, x00, x01, x02, x03, t02);
        if (16 + e >= deg0) t02 = -INFINITY;
        if (a3) {
            LOGIT(U03, x00, x01, x02, x03, t03);
            if (24 + e >= deg0) t03 = -INFINITY;
        }
    }
    if (b2) {
        LOGIT(U12, x10, x11, x12, x13, t12);
        if (16 + e >= deg1) t12 = -INFINITY;
        if (b3) {
            LOGIT(U13, x10, x11, x12, x13, t13);
            if (24 + e >= deg1) t13 = -INFINITY;
        }
    }

    float m0 = emax(fmaxf(fmaxf(t00, t01), fmaxf(t02, t03)));
    float m1 = emax(fmaxf(fmaxf(t10, t11), fmaxf(t12, t13)));

    float p00 = __expf(t00 - m0), p01 = __expf(t01 - m0);
    float p10 = __expf(t10 - m1), p11 = __expf(t11 - m1);
    float l0 = p00 + p01, l1 = p10 + p11;
    float4 oA0 = make_float4(0.f, 0.f, 0.f, 0.f), oB0 = oA0;
    float4 oA1 = oA0, oB1 = oA0;
    {
        h2v pa = {(_Float16)p00, (_Float16)p01};
        h2v pb = {(_Float16)p10, (_Float16)p11};
        PVACC(pa, U00, U01, oA0, oB0)
        PVACC(pb, U10, U11, oA1, oB1)
    }
    if (a2) {
        float p02 = __expf(t02 - m0), p03 = __expf(t03 - m0);
        l0 += p02 + p03;
        h2v pa = {(_Float16)p02, (_Float16)p03};
        PVACC(pa, U02, U03, oA0, oB0)
    }
    if (b2) {
        float p12 = __expf(t12 - m1), p13 = __expf(t13 - m1);
        l1 += p12 + p13;
        h2v pb = {(_Float16)p12, (_Float16)p13};
        PVACC(pb, U12, U13, oA1, oB1)
    }

    // ---- continuation (rare, deg > 32): general online-softmax body ----
#define GENLOOP(LO, DEG, XH0, XH1, XH2, XH3, M, L, OA, OB)                     \
    for (int base = 32; base < DEG; base += 32) {                              \
        const int rem = DEG - base;                                            \
        int s0 = (int)srcs[LO + min(base + e, DEG - 1)];                       \
        int s1 = (int)srcs[LO + min(base + 8 + e, DEG - 1)];                   \
        int s2 = (int)srcs[LO + min(base + 16 + e, DEG - 1)];                  \
        int s3 = (int)srcs[LO + min(base + 24 + e, DEG - 1)];                  \
        uint4 V0 = GATHER(s0), V1 = GATHER(s1), V2, V3;                        \
        float u0, u1, u2 = -INFINITY, u3 = -INFINITY;                          \
        LOGIT(V0, XH0, XH1, XH2, XH3, u0);                                     \
        LOGIT(V1, XH0, XH1, XH2, XH3, u1);                                     \
        if (base + e >= DEG) u0 = -INFINITY;                                   \
        if (base + 8 + e >= DEG) u1 = -INFINITY;                               \
        const bool c2 = rem > 16;                                              \
        if (c2) {                                                              \
            V2 = GATHER(s2);                                                   \
            LOGIT(V2, XH0, XH1, XH2, XH3, u2);                                 \
            if (base + 16 + e >= DEG) u2 = -INFINITY;                          \
            if (rem > 24) {                                                    \
                V3 = GATHER(s3);                                               \
                LOGIT(V3, XH0, XH1, XH2, XH3, u3);                             \
                if (base + 24 + e >= DEG) u3 = -INFINITY;                      \
            } else { V3 = V0; }                                                \
        }                                                                      \
        float cm = emax(fmaxf(fmaxf(u0, u1), fmaxf(u2, u3)));                  \
        if (cm > M) {                                                          \
            float corr = __expf(M - cm);                                       \
            M = cm;                                                            \
            L *= corr;                                                         \
            OA.x *= corr; OA.y *= corr; OA.z *= corr; OA.w *= corr;            \
            OB.x *= corr; OB.y *= corr; OB.z *= corr; OB.w *= corr;            \
        }                                                                      \
        float q0 = __expf(u0 - M), q1 = __expf(u1 - M);                        \
        L += q0 + q1;                                                          \
        h2v qp = {(_Float16)q0, (_Float16)q1};                                 \
        PVACC(qp, V0, V1, OA, OB)                                              \
        if (c2) {                                                              \
            float q2 = __expf(u2 - M), q3 = __expf(u3 - M);                    \
            L += q2 + q3;                                                      \
            h2v qq = {(_Float16)q2, (_Float16)q3};                             \
            PVACC(qq, V2, V3, OA, OB)                                          \
        }                                                                      \
    }

    if (deg0 > 32) { GENLOOP(lo0, deg0, x00, x01, x02, x03, m0, l0, oA0, oB0) }
    if (deg1 > 32) { GENLOOP(lo1, deg1, x10, x11, x12, x13, m1, l1, oA1, oB1) }
#undef GENLOOP
#undef GATHER
#undef LOGIT
#undef PVACC

    // ---- epilogue: interleaved reduces, parallel write (e=0 -> d0, e=1 -> d1)
    l0    = esum(l0);    l1    = esum(l1);
    oA0.x = esum(oA0.x); oA1.x = esum(oA1.x);
    oA0.y = esum(oA0.y); oA1.y = esum(oA1.y);
    oA0.z = esum(oA0.z); oA1.z = esum(oA1.z);
    oA0.w = esum(oA0.w); oA1.w = esum(oA1.w);
    oB0.x = esum(oB0.x); oB1.x = esum(oB1.x);
    oB0.y = esum(oB0.y); oB1.y = esum(oB1.y);
    oB0.z = esum(oB0.z); oB1.z = esum(oB1.z);
    oB0.w = esum(oB0.w); oB1.w = esum(oB1.w);

    if (e < 2) {
        const bool s = (e == 1);
        int dd = s ? d1 : d0;
        float inv = 1.f / (s ? l1 : l0);
        float4 wA = s ? oA1 : oA0;
        float4 wB = s ? oB1 : oB0;
        float4* a4 = (float4*)&acc[(size_t)dd * HID + 8 * cg];
        float4 c0 = a4[0], c1 = a4[1];
        c0.x += wA.x * inv; c0.y += wA.y * inv;
        c0.z += wA.z * inv; c0.w += wA.w * inv;
        c1.x += wB.x * inv; c1.y += wB.y * inv;
        c1.z += wB.z * inv; c1.w += wB.w * inv;
        a4[0] = c0; a4[1] = c1;
    }
}

// ---- fused mean-pool + head ----
__global__ __launch_bounds__(512) void k_pool_final(
        const float* __restrict__ acc,
        const int* __restrict__ startg, const int* __restrict__ endg,
        const float* __restrict__ Wf, const float* __restrict__ bf_,
        float* __restrict__ out) {
    __shared__ float red[8][HID];
    const int g = blockIdx.x;
    const int c = threadIdx.x & 63;
    const int j = threadIdx.x >> 6;
    const int s = startg[g], epos = endg[g];

    float sum = 0.f;
    for (int n = s + j; n < epos; n += 8)
        sum += acc[(size_t)n * HID + c];
    red[j][c] = sum;
    __syncthreads();

    if (threadIdx.x < HID) {
        float tot = 0.f;
#pragma unroll
        for (int w = 0; w < 8; w++) tot += red[w][c];
        float cntf = (float)(epos - s);
        float v = tot / fmaxf(cntf, 1.f) * Wf[c];
#pragma unroll
        for (int o = 32; o; o >>= 1) v += __shfl_xor(v, o, 64);
        if (c == 0) out[g] = v + bf_[0];
    }
}

extern "C" void kernel_launch(void* const* d_in, const int* in_sizes, int n_in,
                              void* d_out, int out_size, void* d_ws, size_t ws_size,
                              hipStream_t stream) {
    const float* x   = (const float*)d_in[0];
    const int* eidx  = (const int*)d_in[1];
    const int* batch = (const int*)d_in[2];
    const int* esrc = eidx;
    const int* edst = eidx + NE;
    const float* Wf  = (const float*)d_in[21];
    const float* bfb = (const float*)d_in[22];

    float* wsf = (float*)d_ws;
    const size_t NN64 = (size_t)NN * HID;
    _Float16* xl16 = (_Float16*)wsf;                // NN64 halfs (slot: NN64 floats)
    _Float16* xr16 = (_Float16*)(wsf + NN64);       // NN64 halfs
    float* acc0   = wsf + 2 * NN64;
    float* acc1   = acc0 + NN64;
    short* Ws0    = (short*)(acc1 + NN64);
    short* Ws1    = Ws0 + 2 * 3 * HID * DIN0;
    short* Ws2    = Ws1 + 2 * 3 * HID * HID;
    int*   ccnt   = (int*)(Ws2 + 2 * 3 * HID * HID);
    int*   startg = ccnt + NN;
    int*   endg   = startg + NG;
    int*   off    = endg + NG;
    int*   part   = off + NN + 1;
    int*   partSc = part + SNB;
    int*   cnt8   = partSc + SNB;                   // 8*NN
    u16*   rank   = (u16*)(cnt8 + 8 * NN);          // NE u16
    u16*   srcs   = rank + NE;                      // NE + NN u16 (self-loops)
    _Float16* attp = (_Float16*)(srcs + NE + NN);   // 3 * 2*HID halfs

    k_prep<<<(NN + 255) / 256, 256, 0, stream>>>(
        (const float*)d_in[3], (const float*)d_in[4], (const float*)d_in[7],
        (const float*)d_in[9], (const float*)d_in[10], (const float*)d_in[13],
        (const float*)d_in[15], (const float*)d_in[16], (const float*)d_in[19],
        (const float*)d_in[5], (const float*)d_in[11], (const float*)d_in[17],
        Ws0, Ws1, Ws2, attp, batch, startg, endg, cnt8);

    // fused: gemm L0 (independent of edges) || hist8 (independent of gemm)
    k_g0_hist<<<G0B + HB, 256, 0, stream>>>(
        x, Ws0, (const float*)d_in[6], (const float*)d_in[8],
        xl16, xr16, acc0, edst, cnt8, rank);

    k_histscan<<<SNB, 256, 0, stream>>>(cnt8, ccnt, part);
    k_scan_emit<<<SNB, 256, 0, stream>>>(ccnt, part, off, srcs);
    k_scatter_rank<<<(NE + 255) / 256, 256, 0, stream>>>(esrc, edst, off, cnt8, rank, srcs);

    const short* Wss[3] = {Ws0, Ws1, Ws2};
    float* accs[4] = {acc0, acc0, acc1, acc0};  // out of layer L = accs[L+1]
    const int gemm_grid = (NN + 63) / 64;
    for (int L = 0; L < 3; L++) {
        const float* b   = (const float*)d_in[3 + L * 6 + 3];
        const float* Rb  = (const float*)d_in[3 + L * 6 + 5];
        float* accOut = accs[L + 1];

        if (L > 0)
            k_gemm<HID, true><<<gemm_grid, 256, 0, stream>>>(
                accs[L], Wss[L], b, Rb, xl16, xr16, accOut);

        k_attn_dst<<<NN / 8, 256, 0, stream>>>(
            off, srcs, xl16, xr16, attp + L * 2 * HID, accOut);
    }

    k_pool_final<<<NG, 512, 0, stream>>>(accs[3], startg, endg, Wf, bfb, (float*)d_out);
}